// Round 5
// baseline (404.563 us; speedup 1.0000x reference)
//
#include <hip/hip_runtime.h>
#include <math.h>

// Problem constants (match reference)
#define BB 1024
#define TT 2048
#define II 2
#define HH 64

// ---- DPP MAC building blocks ----------------------------------------------
// acc += c[row*16+r] * w   with DPP row_newbcast:r broadcasting lane r of each
// 16-lane row of c.
#define FM(a,c,w,r) "v_fmac_f32 " a ", " c ", " w " row_newbcast:" r "\n\t"
#define MU(a,c,w,r) "v_mul_f32 "  a ", " c ", " w " row_newbcast:" r "\n\t"

// Quarter x consumes copy c_x[l] = h[l ^ 16x]; row g sees h[16(g^x)+r] at
// bcast r, matched by weight reg v(12+16x+r) = W[j][16((j>>4)^x)+r] (weights
// loaded column-permuted per lane in the prologue; verified absmax=0.0).
// 8 accumulator chains (v76-79,v94-97), reuse distance 8 instrs.
#define Q0 \
 FM("v76","v80","v12","0")  FM("v77","v80","v13","1")  MU("v78","v80","v14","2")  MU("v79","v80","v15","3") \
 MU("v94","v80","v16","4")  MU("v95","v80","v17","5")  MU("v96","v80","v18","6")  MU("v97","v80","v19","7") \
 FM("v76","v80","v20","8")  FM("v77","v80","v21","9")  FM("v78","v80","v22","10") FM("v79","v80","v23","11") \
 FM("v94","v80","v24","12") FM("v95","v80","v25","13") FM("v96","v80","v26","14") FM("v97","v80","v27","15")
#define Q1 \
 FM("v76","v81","v28","0")  FM("v77","v81","v29","1")  FM("v78","v81","v30","2")  FM("v79","v81","v31","3") \
 FM("v94","v81","v32","4")  FM("v95","v81","v33","5")  FM("v96","v81","v34","6")  FM("v97","v81","v35","7") \
 FM("v76","v81","v36","8")  FM("v77","v81","v37","9")  FM("v78","v81","v38","10") FM("v79","v81","v39","11") \
 FM("v94","v81","v40","12") FM("v95","v81","v41","13") FM("v96","v81","v42","14") FM("v97","v81","v43","15")
#define Q2 \
 FM("v76","v82","v44","0")  FM("v77","v82","v45","1")  FM("v78","v82","v46","2")  FM("v79","v82","v47","3") \
 FM("v94","v82","v48","4")  FM("v95","v82","v49","5")  FM("v96","v82","v50","6")  FM("v97","v82","v51","7") \
 FM("v76","v82","v52","8")  FM("v77","v82","v53","9")  FM("v78","v82","v54","10") FM("v79","v82","v55","11") \
 FM("v94","v82","v56","12") FM("v95","v82","v57","13") FM("v96","v82","v58","14") FM("v97","v82","v59","15")
#define Q3 \
 FM("v76","v83","v60","0")  FM("v77","v83","v61","1")  FM("v78","v83","v62","2")  FM("v79","v83","v63","3") \
 FM("v94","v83","v64","4")  FM("v95","v83","v65","5")  FM("v96","v83","v66","6")  FM("v97","v83","v67","7") \
 FM("v76","v83","v68","8")  FM("v77","v83","v69","9")  FM("v78","v83","v70","10") FM("v79","v83","v71","11") \
 FM("v94","v83","v72","12") FM("v95","v83","v73","13") FM("v96","v83","v74","14") FM("v97","v83","v75","15")

// combine 8 chains + relu -> h (v80)
#define HFIN \
 "v_add_f32 v76, v76, v77\n\t" \
 "v_add_f32 v78, v78, v79\n\t" \
 "v_add_f32 v94, v94, v95\n\t" \
 "v_add_f32 v96, v96, v97\n\t" \
 "v_add_f32 v76, v76, v78\n\t" \
 "v_add_f32 v94, v94, v96\n\t" \
 "v_add_f32 v76, v76, v94\n\t" \
 "v_max_f32 v80, 0, v76\n\t"

// All 3 cross-lane copies issue up-front (each depends only on h):
//   c1 = h^16 (ds_swizzle xor16), c2 = h^32 (bpermute v89), c3 = h^48
//   (bpermute v98). DS ops complete in order -> staged lgkmcnt waits; Q0
//   (direct h via DPP) runs under the latency of the first.
#define MACS \
 Q0 \
 "s_waitcnt lgkmcnt(2)\n\t" \
 Q1 \
 "s_waitcnt lgkmcnt(1)\n\t" \
 Q2 \
 "s_waitcnt lgkmcnt(0)\n\t" \
 Q3 \
 HFIN

// Even step: consume x pair A (v84:85), advance+clamp offset, prefetch into A.
#define STEP_EVEN \
 "ds_swizzle_b32 v81, v80 offset:0x401f\n\t" \
 "ds_bpermute_b32 v82, v89, v80\n\t" \
 "ds_bpermute_b32 v83, v98, v80\n\t" \
 "s_waitcnt vmcnt(1)\n\t" \
 "v_mul_f32 v76, v84, v90\n\t" \
 "v_mul_f32 v77, v85, v91\n\t" \
 "v_add_u32 v88, 16, v88\n\t" \
 "v_min_u32 v88, 0x3ff0, v88\n\t" \
 "global_load_dwordx2 v[84:85], v88, %[xb]\n\t" \
 MACS

// Odd step: consume x pair B (v86:87), prefetch into B at offset+8.
#define STEP_ODD \
 "ds_swizzle_b32 v81, v80 offset:0x401f\n\t" \
 "ds_bpermute_b32 v82, v89, v80\n\t" \
 "ds_bpermute_b32 v83, v98, v80\n\t" \
 "s_waitcnt vmcnt(1)\n\t" \
 "v_mul_f32 v76, v86, v90\n\t" \
 "v_mul_f32 v77, v87, v91\n\t" \
 "global_load_dwordx2 v[86:87], v88, %[xb] offset:8\n\t" \
 MACS

__global__ __launch_bounds__(64, 1) void rnn_scan_kernel(
    const float* __restrict__ x,    // [B, T, 2]
    const float* __restrict__ Wh,   // [64, 64] row-major
    const float* __restrict__ Wx,   // [64, 2]
    float* __restrict__ out)        // [B]
{
    const int b = blockIdx.x;
    const int j = threadIdx.x;   // 0..63, lane == hidden index

    const float* xb = x + (size_t)b * TT * II;

    float h;
    asm volatile(
        // ---- prologue ------------------------------------------------------
        // Column-permuted weight load: w reg v(12+16x+r) = W[j][16((j>>4)^x)+r]
        "v_lshlrev_b32 v92, 8, %[lane]\n\t"        // j*256
        "v_lshrrev_b32 v93, 4, %[lane]\n\t"        // g = j>>4
        "v_lshlrev_b32 v89, 6, v93\n\t"            // (g^0)*64
        "v_add_u32 v89, v92, v89\n\t"
        "global_load_dwordx4 v[12:15], v89, %[wh]\n\t"
        "global_load_dwordx4 v[16:19], v89, %[wh] offset:16\n\t"
        "global_load_dwordx4 v[20:23], v89, %[wh] offset:32\n\t"
        "global_load_dwordx4 v[24:27], v89, %[wh] offset:48\n\t"
        "v_xor_b32 v89, 1, v93\n\t"
        "v_lshlrev_b32 v89, 6, v89\n\t"            // (g^1)*64
        "v_add_u32 v89, v92, v89\n\t"
        "global_load_dwordx4 v[28:31], v89, %[wh]\n\t"
        "global_load_dwordx4 v[32:35], v89, %[wh] offset:16\n\t"
        "global_load_dwordx4 v[36:39], v89, %[wh] offset:32\n\t"
        "global_load_dwordx4 v[40:43], v89, %[wh] offset:48\n\t"
        "v_xor_b32 v89, 2, v93\n\t"
        "v_lshlrev_b32 v89, 6, v89\n\t"            // (g^2)*64
        "v_add_u32 v89, v92, v89\n\t"
        "global_load_dwordx4 v[44:47], v89, %[wh]\n\t"
        "global_load_dwordx4 v[48:51], v89, %[wh] offset:16\n\t"
        "global_load_dwordx4 v[52:55], v89, %[wh] offset:32\n\t"
        "global_load_dwordx4 v[56:59], v89, %[wh] offset:48\n\t"
        "v_xor_b32 v89, 3, v93\n\t"
        "v_lshlrev_b32 v89, 6, v89\n\t"            // (g^3)*64
        "v_add_u32 v89, v92, v89\n\t"
        "global_load_dwordx4 v[60:63], v89, %[wh]\n\t"
        "global_load_dwordx4 v[64:67], v89, %[wh] offset:16\n\t"
        "global_load_dwordx4 v[68:71], v89, %[wh] offset:32\n\t"
        "global_load_dwordx4 v[72:75], v89, %[wh] offset:48\n\t"
        // wx row j -> v90:91
        "v_lshlrev_b32 v89, 3, %[lane]\n\t"
        "global_load_dwordx2 v[90:91], v89, %[wx]\n\t"
        // x prefetch: pair A = x(t=0), pair B = x(t=1)
        "v_mov_b32 v88, 0\n\t"
        "global_load_dwordx2 v[84:85], v88, %[xb]\n\t"
        "global_load_dwordx2 v[86:87], v88, %[xb] offset:8\n\t"
        // bpermute addresses: v89 = (l^32)*4, v98 = (l^48)*4
        "v_xor_b32 v89, 32, %[lane]\n\t"
        "v_lshlrev_b32 v89, 2, v89\n\t"
        "v_xor_b32 v98, 48, %[lane]\n\t"
        "v_lshlrev_b32 v98, 2, v98\n\t"
        "v_mov_b32 v80, 0\n\t"
        "s_movk_i32 s16, 0x400\n\t"
        "s_waitcnt vmcnt(0)\n\t"
        // ---- main loop: 1024 pairs of steps --------------------------------
        "LTOP_%=:\n\t"
        STEP_EVEN
        STEP_ODD
        "s_sub_u32 s16, s16, 1\n\t"
        "s_cmp_lg_u32 s16, 0\n\t"
        "s_cbranch_scc1 LTOP_%=\n\t"
        // ---- epilogue ------------------------------------------------------
        "s_waitcnt vmcnt(0)\n\t"
        "v_mov_b32 %[h], v80\n\t"
        : [h] "=&v"(h)
        : [lane] "v"(j), [wh] "s"(Wh), [xb] "s"(xb), [wx] "s"(Wx)
        : "memory", "scc",
          "v12","v13","v14","v15","v16","v17","v18","v19",
          "v20","v21","v22","v23","v24","v25","v26","v27",
          "v28","v29","v30","v31","v32","v33","v34","v35",
          "v36","v37","v38","v39","v40","v41","v42","v43",
          "v44","v45","v46","v47","v48","v49","v50","v51",
          "v52","v53","v54","v55","v56","v57","v58","v59",
          "v60","v61","v62","v63","v64","v65","v66","v67",
          "v68","v69","v70","v71","v72","v73","v74","v75",
          "v76","v77","v78","v79","v80","v81","v82","v83",
          "v84","v85","v86","v87","v88","v89","v90","v91",
          "v92","v93","v94","v95","v96","v97","v98",
          "s16");

    // ||h_T||_2 across the wave
    float s = h * h;
#pragma unroll
    for (int off = 32; off > 0; off >>= 1)
        s += __shfl_xor(s, off, 64);
    if (j == 0)
        out[b] = sqrtf(s);
}

extern "C" void kernel_launch(void* const* d_in, const int* in_sizes, int n_in,
                              void* d_out, int out_size, void* d_ws, size_t ws_size,
                              hipStream_t stream) {
    const float* x  = (const float*)d_in[0];   // [B,T,2]
    const float* Wh = (const float*)d_in[1];   // [64,64]
    const float* Wx = (const float*)d_in[2];   // [64,2]
    float* out = (float*)d_out;                // [B]

    rnn_scan_kernel<<<dim3(BB), dim3(64), 0, stream>>>(x, Wh, Wx, out);
}

// Round 6
// 395.354 us; speedup vs baseline: 1.0233x; 1.0233x over previous
//
#include <hip/hip_runtime.h>
#include <math.h>

// Problem constants (match reference)
#define BB 1024
#define TT 2048
#define II 2
#define HH 64

// ---- DPP MAC building blocks ----------------------------------------------
// acc += c[row16*16+r] * w  with DPP row_newbcast:r broadcasting lane r of
// each 16-lane row of c.
#define FM(a,c,w,r) "v_fmac_f32 " a ", " c ", " w " row_newbcast:" r "\n\t"
#define MU(a,c,w,r) "v_mul_f32 "  a ", " c ", " w " row_newbcast:" r "\n\t"

// 2-wave k-split: wave w holds rotated state hw[l] = h[l ^ 32w] in v80 and
// covers k-groups {g^2w, g^2w^1} (g = l>>4) via quarters x=0 (copy hw) and
// x=1 (copy hw^16, one ds_swizzle). Weights are loaded group-permuted per
// wave/lane so register naming is uniform: v(12+16x+r) = W[l][16(g^2w^x)+r].
// 4 acc chains v76-79; chain0 is initialized by the x-term mul.
#define Q0 \
 FM("v76","v80","v12","0")  MU("v77","v80","v13","1")  MU("v78","v80","v14","2")  MU("v79","v80","v15","3") \
 FM("v76","v80","v16","4")  FM("v77","v80","v17","5")  FM("v78","v80","v18","6")  FM("v79","v80","v19","7") \
 FM("v76","v80","v20","8")  FM("v77","v80","v21","9")  FM("v78","v80","v22","10") FM("v79","v80","v23","11") \
 FM("v76","v80","v24","12") FM("v77","v80","v25","13") FM("v78","v80","v26","14") FM("v79","v80","v27","15")
#define Q1 \
 FM("v76","v81","v28","0")  FM("v77","v81","v29","1")  FM("v78","v81","v30","2")  FM("v79","v81","v31","3") \
 FM("v76","v81","v32","4")  FM("v77","v81","v33","5")  FM("v78","v81","v34","6")  FM("v79","v81","v35","7") \
 FM("v76","v81","v36","8")  FM("v77","v81","v37","9")  FM("v78","v81","v38","10") FM("v79","v81","v39","11") \
 FM("v76","v81","v40","12") FM("v77","v81","v41","13") FM("v78","v81","v42","14") FM("v79","v81","v43","15")

// Combine own half, publish to LDS, barrier, read both halves (A at +0,
// B at +256B = 64 dwords), finish: h = relu(A+B). Parity double-buffer:
// even uses bytes [0,512), odd uses [512,1024) -> one barrier per step is
// race-free (a wave running ahead writes the opposite-parity buffer).
#define TAIL(WROFF, O0, O1) \
 "v_add_f32 v76, v76, v77\n\t" \
 "v_add_f32 v78, v78, v79\n\t" \
 "v_add_f32 v76, v76, v78\n\t" \
 "ds_write_b32 v96, v76" WROFF "\n\t" \
 "s_waitcnt lgkmcnt(0)\n\t" \
 "s_barrier\n\t" \
 "ds_read2_b32 v[76:77], v97 offset0:" O0 " offset1:" O1 "\n\t" \
 "s_waitcnt lgkmcnt(0)\n\t" \
 "v_add_f32 v76, v76, v77\n\t" \
 "v_max_f32 v80, 0, v76\n\t"

// Even step: consume x elem (v84), advance+clamp ptr, prefetch t+2's elem.
// Clamp 0x3ff4: all legitimately-consumed addresses (max 0x3ff4 for w=1)
// are below/equal; overrun prefetches stay in-bounds and are never consumed.
#define STEP_EVEN \
 "ds_swizzle_b32 v81, v80 offset:0x401f\n\t" \
 "s_waitcnt vmcnt(1)\n\t" \
 "v_mul_f32 v76, v84, v90\n\t" \
 "v_add_u32 v88, 16, v88\n\t" \
 "v_min_u32 v88, 0x3ff4, v88\n\t" \
 "global_load_dword v84, v88, %[xb]\n\t" \
 Q0 \
 "s_waitcnt lgkmcnt(0)\n\t" \
 Q1 \
 TAIL("", "0", "64")

// Odd step: consume v86, prefetch at v88+8 (t+3's elem), odd-parity LDS.
#define STEP_ODD \
 "ds_swizzle_b32 v81, v80 offset:0x401f\n\t" \
 "s_waitcnt vmcnt(1)\n\t" \
 "v_mul_f32 v76, v86, v90\n\t" \
 "global_load_dword v86, v88, %[xb] offset:8\n\t" \
 Q0 \
 "s_waitcnt lgkmcnt(0)\n\t" \
 Q1 \
 TAIL(" offset:512", "128", "192")

__global__ __launch_bounds__(128) void rnn_scan_kernel(
    const float* __restrict__ x,    // [B, T, 2]
    const float* __restrict__ Wh,   // [64, 64] row-major
    const float* __restrict__ Wx,   // [64, 2]
    float* __restrict__ out)        // [B]
{
    extern __shared__ float lds[];  // 256 floats: A/B even at 0/256B, odd at 512/768B

    const int b   = blockIdx.x;
    const int tid = threadIdx.x;
    const int l   = tid & 63;        // lane = output row j
    const int w   = tid >> 6;        // wave id: k-half owner
    const int g   = l >> 4;

    const float* xb = x + (size_t)b * TT * II;

    // Per-wave addresses (computed in C, passed into fixed-reg asm):
    const unsigned wa0 = (unsigned)(l * 256 + ((g ^ (w << 1)) << 6));      // quarter 0 row base
    const unsigned wa1 = (unsigned)(l * 256 + ((g ^ (w << 1) ^ 1) << 6));  // quarter 1 row base
    const unsigned wxa = (unsigned)(l * 8 + w * 4);                        // Wx[l][w]
    const unsigned xi  = (unsigned)(w * 4);                                // x elem-w byte offset
    const unsigned wr  = (unsigned)(w * 256 + l * 4);                      // partial write slot
    const unsigned rd  = (unsigned)((l ^ (w << 5)) * 4);                   // read base (rotated for w=1)

    float h;
    asm volatile(
        // ---- prologue: 2 weight quarters -> v12..v43, wx -> v90, x t0/t1 ----
        "global_load_dwordx4 v[12:15], %[wa0], %[wh]\n\t"
        "global_load_dwordx4 v[16:19], %[wa0], %[wh] offset:16\n\t"
        "global_load_dwordx4 v[20:23], %[wa0], %[wh] offset:32\n\t"
        "global_load_dwordx4 v[24:27], %[wa0], %[wh] offset:48\n\t"
        "global_load_dwordx4 v[28:31], %[wa1], %[wh]\n\t"
        "global_load_dwordx4 v[32:35], %[wa1], %[wh] offset:16\n\t"
        "global_load_dwordx4 v[36:39], %[wa1], %[wh] offset:32\n\t"
        "global_load_dwordx4 v[40:43], %[wa1], %[wh] offset:48\n\t"
        "global_load_dword v90, %[wxa], %[wx]\n\t"
        "v_mov_b32 v88, %[xi]\n\t"
        "global_load_dword v84, v88, %[xb]\n\t"           // x(t=0) elem w
        "global_load_dword v86, v88, %[xb] offset:8\n\t"  // x(t=1) elem w
        "v_mov_b32 v96, %[wr]\n\t"
        "v_mov_b32 v97, %[rd]\n\t"
        "v_mov_b32 v80, 0\n\t"                            // h = 0
        "s_movk_i32 s16, 0x400\n\t"
        "s_waitcnt vmcnt(0)\n\t"
        // ---- main loop: 1024 pairs of steps --------------------------------
        "LTOP_%=:\n\t"
        STEP_EVEN
        STEP_ODD
        "s_sub_u32 s16, s16, 1\n\t"
        "s_cmp_lg_u32 s16, 0\n\t"
        "s_cbranch_scc1 LTOP_%=\n\t"
        // ---- epilogue ------------------------------------------------------
        "s_waitcnt vmcnt(0)\n\t"
        "v_mov_b32 %[h], v80\n\t"
        : [h] "=&v"(h)
        : [wa0] "v"(wa0), [wa1] "v"(wa1), [wxa] "v"(wxa), [xi] "v"(xi),
          [wr] "v"(wr), [rd] "v"(rd),
          [wh] "s"(Wh), [xb] "s"(xb), [wx] "s"(Wx)
        : "memory", "scc",
          "v12","v13","v14","v15","v16","v17","v18","v19",
          "v20","v21","v22","v23","v24","v25","v26","v27",
          "v28","v29","v30","v31","v32","v33","v34","v35",
          "v36","v37","v38","v39","v40","v41","v42","v43",
          "v76","v77","v78","v79","v80","v81","v84","v86",
          "v88","v90","v96","v97",
          "s16");

    // ||h_T||_2: each wave's v80 holds a permutation of h -> same sum.
    float s = h * h;
#pragma unroll
    for (int off = 32; off > 0; off >>= 1)
        s += __shfl_xor(s, off, 64);
    if (tid == 0)
        out[b] = sqrtf(s);
}

extern "C" void kernel_launch(void* const* d_in, const int* in_sizes, int n_in,
                              void* d_out, int out_size, void* d_ws, size_t ws_size,
                              hipStream_t stream) {
    const float* x  = (const float*)d_in[0];   // [B,T,2]
    const float* Wh = (const float*)d_in[1];   // [64,64]
    const float* Wx = (const float*)d_in[2];   // [64,2]
    float* out = (float*)d_out;                // [B]

    rnn_scan_kernel<<<dim3(BB), dim3(128), 1024, stream>>>(x, Wh, Wx, out);
}

// Round 8
// 337.341 us; speedup vs baseline: 1.1993x; 1.1720x over previous
//
#include <hip/hip_runtime.h>
#include <math.h>

// Problem constants (match reference)
#define BB 1024
#define TT 2048
#define II 2
#define HH 64

// ---- DPP MAC ---------------------------------------------------------------
// acc (+)= Rq[row*16+r] * w  with DPP row_newbcast:r. Rq is a full-broadcast
// register; which h-group each register holds is PROBED at runtime (prologue)
// and the weight banks are loaded to match -> convention-independent.
#define FM(a,c,w,r) "v_fmac_f32 " a ", " c ", " w " row_newbcast:" r "\n\t"
#define MU(a,c,w,r) "v_mul_f32 "  a ", " c ", " w " row_newbcast:" r "\n\t"

#define Q0 \
 FM("v76","v80","v12","0")  MU("v77","v80","v13","1")  MU("v78","v80","v14","2")  MU("v79","v80","v15","3") \
 FM("v76","v80","v16","4")  FM("v77","v80","v17","5")  FM("v78","v80","v18","6")  FM("v79","v80","v19","7") \
 FM("v76","v80","v20","8")  FM("v77","v80","v21","9")  FM("v78","v80","v22","10") FM("v79","v80","v23","11") \
 FM("v76","v80","v24","12") FM("v77","v80","v25","13") FM("v78","v80","v26","14") FM("v79","v80","v27","15")
#define Q1 \
 FM("v76","v81","v28","0")  FM("v77","v81","v29","1")  FM("v78","v81","v30","2")  FM("v79","v81","v31","3") \
 FM("v76","v81","v32","4")  FM("v77","v81","v33","5")  FM("v78","v81","v34","6")  FM("v79","v81","v35","7") \
 FM("v76","v81","v36","8")  FM("v77","v81","v37","9")  FM("v78","v81","v38","10") FM("v79","v81","v39","11") \
 FM("v76","v81","v40","12") FM("v77","v81","v41","13") FM("v78","v81","v42","14") FM("v79","v81","v43","15")
#define Q2 \
 FM("v76","v82","v44","0")  FM("v77","v82","v45","1")  FM("v78","v82","v46","2")  FM("v79","v82","v47","3") \
 FM("v76","v82","v48","4")  FM("v77","v82","v49","5")  FM("v78","v82","v50","6")  FM("v79","v82","v51","7") \
 FM("v76","v82","v52","8")  FM("v77","v82","v53","9")  FM("v78","v82","v54","10") FM("v79","v82","v55","11") \
 FM("v76","v82","v56","12") FM("v77","v82","v57","13") FM("v78","v82","v58","14") FM("v79","v82","v59","15")
#define Q3 \
 FM("v76","v83","v60","0")  FM("v77","v83","v61","1")  FM("v78","v83","v62","2")  FM("v79","v83","v63","3") \
 FM("v76","v83","v64","4")  FM("v77","v83","v65","5")  FM("v78","v83","v66","6")  FM("v79","v83","v67","7") \
 FM("v76","v83","v68","8")  FM("v77","v83","v69","9")  FM("v78","v83","v70","10") FM("v79","v83","v71","11") \
 FM("v76","v83","v72","12") FM("v77","v83","v73","13") FM("v78","v83","v74","14") FM("v79","v83","v75","15")

// combine 4 chains + relu into BOTH v80,v81 (the two p16 operands next step)
#define TAIL \
 "v_add_f32 v76, v76, v77\n\t" \
 "v_add_f32 v78, v78, v79\n\t" \
 "v_add_f32 v76, v76, v78\n\t" \
 "v_max_f32 v80, 0, v76\n\t" \
 "v_max_f32 v81, 0, v76\n\t"

// The swap tree (identical sequence as the prologue probe). s_nops guard the
// VALU-write -> permlane/DPP-source hazards (raw asm gets no compiler nops).
// x terms come straight from SGPR banks (SMEM-loaded) as VOP2 src0.
#define STEP(SX0, SX1) \
 "s_nop 1\n\t" \
 "v_permlane16_swap_b32 v80, v81\n\t" \
 "s_nop 1\n\t" \
 "v_mov_b32 v82, v80\n\t" \
 "v_mov_b32 v83, v81\n\t" \
 "s_nop 0\n\t" \
 "v_permlane32_swap_b32 v80, v82\n\t" \
 "v_permlane32_swap_b32 v81, v83\n\t" \
 "s_nop 1\n\t" \
 "v_mul_f32 v76, " SX0 ", v90\n\t" \
 "v_fmac_f32 v76, " SX1 ", v91\n\t" \
 Q0 Q1 Q2 Q3 \
 TAIL

#define STEPS_A \
 STEP("s36","s37") STEP("s38","s39") STEP("s40","s41") STEP("s42","s43") \
 STEP("s44","s45") STEP("s46","s47") STEP("s48","s49") STEP("s50","s51")
#define STEPS_B \
 STEP("s52","s53") STEP("s54","s55") STEP("s56","s57") STEP("s58","s59") \
 STEP("s60","s61") STEP("s62","s63") STEP("s64","s65") STEP("s66","s67")

__global__ __launch_bounds__(64, 1) void rnn_scan_kernel(
    const float* __restrict__ x,    // [B, T, 2]
    const float* __restrict__ Wh,   // [64, 64] row-major
    const float* __restrict__ Wx,   // [64, 2]
    float* __restrict__ out)        // [B]
{
    const int b = blockIdx.x;
    const int j = threadIdx.x;   // 0..63, lane == hidden index

    const float* xb = x + (size_t)b * TT * II;

    float h;
    asm volatile(
        // ---- PROBE: discover which h-group each tree output broadcasts -----
        "v_lshrrev_b32 v80, 4, %[lane]\n\t"        // value = group id g
        "v_mov_b32 v81, v80\n\t"
        "s_nop 7\n\t"
        "v_permlane16_swap_b32 v80, v81\n\t"
        "s_nop 7\n\t"
        "v_mov_b32 v82, v80\n\t"
        "v_mov_b32 v83, v81\n\t"
        "s_nop 7\n\t"
        "v_permlane32_swap_b32 v80, v82\n\t"
        "v_permlane32_swap_b32 v81, v83\n\t"
        "s_nop 7\n\t"
        "v_readfirstlane_b32 s4, v80\n\t"          // m0: group in v80
        "s_nop 7\n\t"
        "v_readfirstlane_b32 s5, v81\n\t"          // m1
        "v_readfirstlane_b32 s6, v82\n\t"          // m2
        "v_readfirstlane_b32 s7, v83\n\t"          // m3
        // ---- weight banks: bank q <- W[j][16*mq .. 16*mq+15] ---------------
        "v_lshlrev_b32 v92, 8, %[lane]\n\t"        // j*256
        "s_lshl_b32 s9, s4, 6\n\t"
        "v_add_u32 v93, s9, v92\n\t"
        "global_load_dwordx4 v[12:15], v93, %[wh]\n\t"
        "global_load_dwordx4 v[16:19], v93, %[wh] offset:16\n\t"
        "global_load_dwordx4 v[20:23], v93, %[wh] offset:32\n\t"
        "global_load_dwordx4 v[24:27], v93, %[wh] offset:48\n\t"
        "s_lshl_b32 s9, s5, 6\n\t"
        "v_add_u32 v93, s9, v92\n\t"
        "global_load_dwordx4 v[28:31], v93, %[wh]\n\t"
        "global_load_dwordx4 v[32:35], v93, %[wh] offset:16\n\t"
        "global_load_dwordx4 v[36:39], v93, %[wh] offset:32\n\t"
        "global_load_dwordx4 v[40:43], v93, %[wh] offset:48\n\t"
        "s_lshl_b32 s9, s6, 6\n\t"
        "v_add_u32 v93, s9, v92\n\t"
        "global_load_dwordx4 v[44:47], v93, %[wh]\n\t"
        "global_load_dwordx4 v[48:51], v93, %[wh] offset:16\n\t"
        "global_load_dwordx4 v[52:55], v93, %[wh] offset:32\n\t"
        "global_load_dwordx4 v[56:59], v93, %[wh] offset:48\n\t"
        "s_lshl_b32 s9, s7, 6\n\t"
        "v_add_u32 v93, s9, v92\n\t"
        "global_load_dwordx4 v[60:63], v93, %[wh]\n\t"
        "global_load_dwordx4 v[64:67], v93, %[wh] offset:16\n\t"
        "global_load_dwordx4 v[68:71], v93, %[wh] offset:32\n\t"
        "global_load_dwordx4 v[72:75], v93, %[wh] offset:48\n\t"
        // wx row j -> v90:91
        "v_lshlrev_b32 v93, 3, %[lane]\n\t"
        "global_load_dwordx2 v[90:91], v93, %[wx]\n\t"
        // x block 0 via SMEM (8 steps = 64B); double-banked thereafter
        "s_mov_b64 s[10:11], %[xb]\n\t"
        "s_load_dwordx16 s[36:51], s[10:11], 0x0\n\t"
        // h init (dual), loop counter = 128 blocks of 16 steps
        "v_mov_b32 v80, 0\n\t"
        "v_mov_b32 v81, 0\n\t"
        "s_movk_i32 s16, 128\n\t"
        "s_waitcnt vmcnt(0) lgkmcnt(0)\n\t"
        // ---- main loop -----------------------------------------------------
        "LTOP_%=:\n\t"
        "s_load_dwordx16 s[52:67], s[10:11], 0x40\n\t"   // steps 8-15 of block
        STEPS_A
        "s_waitcnt lgkmcnt(0)\n\t"
        "s_cmp_lg_u32 s16, 1\n\t"
        "s_cbranch_scc0 LSKIP_%=\n\t"                     // last block: no +0x80
        "s_load_dwordx16 s[36:51], s[10:11], 0x80\n\t"   // next block steps 0-7
        "LSKIP_%=:\n\t"
        STEPS_B
        "s_waitcnt lgkmcnt(0)\n\t"
        "s_add_u32 s10, s10, 0x80\n\t"
        "s_addc_u32 s11, s11, 0\n\t"
        "s_sub_u32 s16, s16, 1\n\t"
        "s_cmp_lg_u32 s16, 0\n\t"
        "s_cbranch_scc1 LTOP_%=\n\t"
        // ---- epilogue ------------------------------------------------------
        "v_mov_b32 %[h], v80\n\t"
        : [h] "=&v"(h)
        : [lane] "v"(j), [wh] "s"(Wh), [xb] "s"(xb), [wx] "s"(Wx)
        : "memory", "scc",
          "v12","v13","v14","v15","v16","v17","v18","v19",
          "v20","v21","v22","v23","v24","v25","v26","v27",
          "v28","v29","v30","v31","v32","v33","v34","v35",
          "v36","v37","v38","v39","v40","v41","v42","v43",
          "v44","v45","v46","v47","v48","v49","v50","v51",
          "v52","v53","v54","v55","v56","v57","v58","v59",
          "v60","v61","v62","v63","v64","v65","v66","v67",
          "v68","v69","v70","v71","v72","v73","v74","v75",
          "v76","v77","v78","v79","v80","v81","v82","v83",
          "v90","v91","v92","v93",
          "s4","s5","s6","s7","s9","s10","s11","s16",
          "s36","s37","s38","s39","s40","s41","s42","s43",
          "s44","s45","s46","s47","s48","s49","s50","s51",
          "s52","s53","s54","s55","s56","s57","s58","s59",
          "s60","s61","s62","s63","s64","s65","s66","s67");

    // ||h_T||_2 across the wave
    float s = h * h;
#pragma unroll
    for (int off = 32; off > 0; off >>= 1)
        s += __shfl_xor(s, off, 64);
    if (j == 0)
        out[b] = sqrtf(s);
}

extern "C" void kernel_launch(void* const* d_in, const int* in_sizes, int n_in,
                              void* d_out, int out_size, void* d_ws, size_t ws_size,
                              hipStream_t stream) {
    const float* x  = (const float*)d_in[0];   // [B,T,2]
    const float* Wh = (const float*)d_in[1];   // [64,64]
    const float* Wx = (const float*)d_in[2];   // [64,2]
    float* out = (float*)d_out;                // [B]

    rnn_scan_kernel<<<dim3(BB), dim3(64), 0, stream>>>(x, Wh, Wx, out);
}

// Round 11
// 330.986 us; speedup vs baseline: 1.2223x; 1.0192x over previous
//
#include <hip/hip_runtime.h>
#include <math.h>

// Problem constants (match reference)
#define BB 1024
#define TT 2048
#define II 2
#define HH 64

// ---- packed-f32 MAC building blocks ----------------------------------------
// Broadcast mechanism: h written to LDS (lane k -> lds[4k]) once per step,
// then ds_read_b128 at a WAVE-UNIFORM address (v87=0) broadcasts 4 h values
// to all lanes per read (same-address LDS = conflict-free broadcast, m136).
// 16 reads deliver h[0..63] into v128..v191 as naturally-aligned f32 pairs,
// feeding v_pk_fma_f32 (2 full-precision f32 FMAs per instruction):
//   acc pair += (h[2i],h[2i+1]) * (W[j][2i],W[j][2i+1])
// 32 pk instrs replace 64 fmacs. DS ops are in-order per wave -> the write
// completes before the reads see the address; staged lgkmcnt hides latency.
#define PKF(A0,A1,B0,B1,W0,W1) \
 "v_pk_fma_f32 v[" A0 ":" A1 "], v[" B0 ":" B1 "], v[" W0 ":" W1 "], v[" A0 ":" A1 "]\n\t"
#define PKM(A0,A1,B0,B1,W0,W1) \
 "v_pk_mul_f32 v[" A0 ":" A1 "], v[" B0 ":" B1 "], v[" W0 ":" W1 "]\n\t"

#define RD8_LO \
 "ds_read_b128 v[128:131], v87\n\t" \
 "ds_read_b128 v[132:135], v87 offset:16\n\t" \
 "ds_read_b128 v[136:139], v87 offset:32\n\t" \
 "ds_read_b128 v[140:143], v87 offset:48\n\t" \
 "ds_read_b128 v[144:147], v87 offset:64\n\t" \
 "ds_read_b128 v[148:151], v87 offset:80\n\t" \
 "ds_read_b128 v[152:155], v87 offset:96\n\t" \
 "ds_read_b128 v[156:159], v87 offset:112\n\t"

#define RD8_HI \
 "ds_read_b128 v[160:163], v87 offset:128\n\t" \
 "ds_read_b128 v[164:167], v87 offset:144\n\t" \
 "ds_read_b128 v[168:171], v87 offset:160\n\t" \
 "ds_read_b128 v[172:175], v87 offset:176\n\t" \
 "ds_read_b128 v[176:179], v87 offset:192\n\t" \
 "ds_read_b128 v[180:183], v87 offset:208\n\t" \
 "ds_read_b128 v[184:187], v87 offset:224\n\t" \
 "ds_read_b128 v[188:191], v87 offset:240\n\t"

// 4 packed acc chains (v76-83), chain = i&3, reuse distance 4 instrs.
#define MAC_0_9 \
 PKM("76","77","128","129","12","13") \
 PKM("78","79","130","131","14","15") \
 PKM("80","81","132","133","16","17") \
 PKM("82","83","134","135","18","19") \
 PKF("76","77","136","137","20","21") \
 PKF("78","79","138","139","22","23") \
 PKF("80","81","140","141","24","25") \
 PKF("82","83","142","143","26","27") \
 PKF("76","77","144","145","28","29") \
 PKF("78","79","146","147","30","31")
#define MAC_10_15 \
 PKF("80","81","148","149","32","33") \
 PKF("82","83","150","151","34","35") \
 PKF("76","77","152","153","36","37") \
 PKF("78","79","154","155","38","39") \
 PKF("80","81","156","157","40","41") \
 PKF("82","83","158","159","42","43")
#define MAC_16_23 \
 PKF("76","77","160","161","44","45") \
 PKF("78","79","162","163","46","47") \
 PKF("80","81","164","165","48","49") \
 PKF("82","83","166","167","50","51") \
 PKF("76","77","168","169","52","53") \
 PKF("78","79","170","171","54","55") \
 PKF("80","81","172","173","56","57") \
 PKF("82","83","174","175","58","59")
#define MAC_24_31 \
 PKF("76","77","176","177","60","61") \
 PKF("78","79","178","179","62","63") \
 PKF("80","81","180","181","64","65") \
 PKF("82","83","182","183","66","67") \
 PKF("76","77","184","185","68","69") \
 PKF("78","79","186","187","70","71") \
 PKF("80","81","188","189","72","73") \
 PKF("82","83","190","191","74","75")

// combine 4 packed chains -> scalar, add x-seed, relu -> h (v84)
#define TAIL \
 "v_pk_add_f32 v[76:77], v[76:77], v[78:79]\n\t" \
 "v_pk_add_f32 v[80:81], v[80:81], v[82:83]\n\t" \
 "v_pk_add_f32 v[76:77], v[76:77], v[80:81]\n\t" \
 "v_add_f32 v84, v76, v77\n\t" \
 "v_add_f32 v84, v84, v85\n\t" \
 "v_max_f32 v84, 0, v84\n\t"

// Even step: consume x pair A (v96:97), advance+clamp offset, prefetch into A.
// (x pipeline identical to r4's proven scheme: dwordx2 ping-pong, vmcnt(1),
// clamp 0x3ff0 keeps overrun prefetches in-bounds and never consumed.)
#define STEP_EVEN \
 "ds_write_b32 v86, v84\n\t" \
 RD8_LO \
 "s_waitcnt vmcnt(1)\n\t" \
 "v_mul_f32 v85, v96, v90\n\t" \
 "v_fmac_f32 v85, v97, v91\n\t" \
 "v_add_u32 v100, 16, v100\n\t" \
 "v_min_u32 v100, 0x3ff0, v100\n\t" \
 "global_load_dwordx2 v[96:97], v100, %[xb]\n\t" \
 "s_waitcnt lgkmcnt(4)\n\t" \
 RD8_HI \
 MAC_0_9 \
 "s_waitcnt lgkmcnt(8)\n\t" \
 MAC_10_15 \
 "s_waitcnt lgkmcnt(4)\n\t" \
 MAC_16_23 \
 "s_waitcnt lgkmcnt(0)\n\t" \
 MAC_24_31 \
 TAIL

// Odd step: consume x pair B (v98:99), prefetch into B at offset+8.
#define STEP_ODD \
 "ds_write_b32 v86, v84\n\t" \
 RD8_LO \
 "s_waitcnt vmcnt(1)\n\t" \
 "v_mul_f32 v85, v98, v90\n\t" \
 "v_fmac_f32 v85, v99, v91\n\t" \
 "global_load_dwordx2 v[98:99], v100, %[xb] offset:8\n\t" \
 "s_waitcnt lgkmcnt(4)\n\t" \
 RD8_HI \
 MAC_0_9 \
 "s_waitcnt lgkmcnt(8)\n\t" \
 MAC_10_15 \
 "s_waitcnt lgkmcnt(4)\n\t" \
 MAC_16_23 \
 "s_waitcnt lgkmcnt(0)\n\t" \
 MAC_24_31 \
 TAIL

__global__ __launch_bounds__(64, 1) void rnn_scan_kernel(
    const float* __restrict__ x,    // [B, T, 2]
    const float* __restrict__ Wh,   // [64, 64] row-major
    const float* __restrict__ Wx,   // [64, 2]
    float* __restrict__ out)        // [B]
{
    extern __shared__ float lds[];  // 64 floats @ offset 0 (asm addresses 0..255)

    const int b = blockIdx.x;
    const int j = threadIdx.x;   // 0..63, lane == hidden/output index

    const float* xb = x + (size_t)b * TT * II;

    float h;
    asm volatile(
        // ---- prologue: natural-order W row j -> v12..v75 -------------------
        "v_lshlrev_b32 v101, 8, %[lane]\n\t"       // j*256
        "global_load_dwordx4 v[12:15], v101, %[wh]\n\t"
        "global_load_dwordx4 v[16:19], v101, %[wh] offset:16\n\t"
        "global_load_dwordx4 v[20:23], v101, %[wh] offset:32\n\t"
        "global_load_dwordx4 v[24:27], v101, %[wh] offset:48\n\t"
        "global_load_dwordx4 v[28:31], v101, %[wh] offset:64\n\t"
        "global_load_dwordx4 v[32:35], v101, %[wh] offset:80\n\t"
        "global_load_dwordx4 v[36:39], v101, %[wh] offset:96\n\t"
        "global_load_dwordx4 v[40:43], v101, %[wh] offset:112\n\t"
        "global_load_dwordx4 v[44:47], v101, %[wh] offset:128\n\t"
        "global_load_dwordx4 v[48:51], v101, %[wh] offset:144\n\t"
        "global_load_dwordx4 v[52:55], v101, %[wh] offset:160\n\t"
        "global_load_dwordx4 v[56:59], v101, %[wh] offset:176\n\t"
        "global_load_dwordx4 v[60:63], v101, %[wh] offset:192\n\t"
        "global_load_dwordx4 v[64:67], v101, %[wh] offset:208\n\t"
        "global_load_dwordx4 v[68:71], v101, %[wh] offset:224\n\t"
        "global_load_dwordx4 v[72:75], v101, %[wh] offset:240\n\t"
        // wx row j -> v90:91
        "v_lshlrev_b32 v102, 3, %[lane]\n\t"
        "global_load_dwordx2 v[90:91], v102, %[wx]\n\t"
        // x prefetch: pair A = x(t=0), pair B = x(t=1)
        "v_mov_b32 v100, 0\n\t"
        "global_load_dwordx2 v[96:97], v100, %[xb]\n\t"
        "global_load_dwordx2 v[98:99], v100, %[xb] offset:8\n\t"
        // LDS addresses: write = lane*4, read = 0 (uniform broadcast)
        "v_lshlrev_b32 v86, 2, %[lane]\n\t"
        "v_mov_b32 v87, 0\n\t"
        // h init, loop counter
        "v_mov_b32 v84, 0\n\t"
        "s_movk_i32 s16, 0x400\n\t"
        "s_waitcnt vmcnt(0)\n\t"
        // ---- main loop: 1024 pairs of steps --------------------------------
        "LTOP_%=:\n\t"
        STEP_EVEN
        STEP_ODD
        "s_sub_u32 s16, s16, 1\n\t"
        "s_cmp_lg_u32 s16, 0\n\t"
        "s_cbranch_scc1 LTOP_%=\n\t"
        // ---- epilogue ------------------------------------------------------
        "s_waitcnt vmcnt(0)\n\t"
        "v_mov_b32 %[h], v84\n\t"
        : [h] "=&v"(h)
        : [lane] "v"(j), [wh] "s"(Wh), [xb] "s"(xb), [wx] "s"(Wx)
        : "memory", "scc",
          "v12","v13","v14","v15","v16","v17","v18","v19",
          "v20","v21","v22","v23","v24","v25","v26","v27",
          "v28","v29","v30","v31","v32","v33","v34","v35",
          "v36","v37","v38","v39","v40","v41","v42","v43",
          "v44","v45","v46","v47","v48","v49","v50","v51",
          "v52","v53","v54","v55","v56","v57","v58","v59",
          "v60","v61","v62","v63","v64","v65","v66","v67",
          "v68","v69","v70","v71","v72","v73","v74","v75",
          "v76","v77","v78","v79","v80","v81","v82","v83",
          "v84","v85","v86","v87","v90","v91",
          "v96","v97","v98","v99","v100","v101","v102",
          "v128","v129","v130","v131","v132","v133","v134","v135",
          "v136","v137","v138","v139","v140","v141","v142","v143",
          "v144","v145","v146","v147","v148","v149","v150","v151",
          "v152","v153","v154","v155","v156","v157","v158","v159",
          "v160","v161","v162","v163","v164","v165","v166","v167",
          "v168","v169","v170","v171","v172","v173","v174","v175",
          "v176","v177","v178","v179","v180","v181","v182","v183",
          "v184","v185","v186","v187","v188","v189","v190","v191",
          "s16");

    // ||h_T||_2 across the wave (v84 = h[j] at lane j)
    float s = h * h;
#pragma unroll
    for (int off = 32; off > 0; off >>= 1)
        s += __shfl_xor(s, off, 64);
    if (j == 0)
        out[b] = sqrtf(s);
}

extern "C" void kernel_launch(void* const* d_in, const int* in_sizes, int n_in,
                              void* d_out, int out_size, void* d_ws, size_t ws_size,
                              hipStream_t stream) {
    const float* x  = (const float*)d_in[0];   // [B,T,2]
    const float* Wh = (const float*)d_in[1];   // [64,64]
    const float* Wx = (const float*)d_in[2];   // [64,2]
    float* out = (float*)d_out;                // [B]

    rnn_scan_kernel<<<dim3(BB), dim3(64), 256, stream>>>(x, Wh, Wx, out);
}

// Round 13
// 303.316 us; speedup vs baseline: 1.3338x; 1.0912x over previous
//
#include <hip/hip_runtime.h>
#include <math.h>

// Problem constants (match reference)
#define BB 1024
#define TT 2048
#define II 2
#define HH 64

// ---- packed-f32 MAC --------------------------------------------------------
// Broadcast: h written to LDS (lane k -> byte 4k) once per step, read back
// via 16 ds_read_b128 at a wave-uniform address (same-addr LDS = free
// broadcast). v_pk_fma_f32 = 2 exact f32 FMAs/instr -> 32 MACs for 64 terms.
// Model (r3/r5/r8/r11 regression): wall = 4*N + L_exposed; this round
// minimizes L by filling the write->read turnaround with all independent
// work and staging rigorous lgkm waits (12/8/4/0).
// r12 bug fixed here: pk0's C operand is NOW ACTUALLY v[92:93] (the x-seed
// pair) -- r12 left it as v[76:77], compounding the accumulator across
// steps -> inf.
#define PKF(A0,A1,B0,B1,W0,W1) \
 "v_pk_fma_f32 v[" A0 ":" A1 "], v[" B0 ":" B1 "], v[" W0 ":" W1 "], v[" A0 ":" A1 "]\n\t"
#define PKM(A0,A1,B0,B1,W0,W1) \
 "v_pk_mul_f32 v[" A0 ":" A1 "], v[" B0 ":" B1 "], v[" W0 ":" W1 "]\n\t"

#define RD16 \
 "ds_read_b128 v[128:131], v88\n\t" \
 "ds_read_b128 v[132:135], v88 offset:16\n\t" \
 "ds_read_b128 v[136:139], v88 offset:32\n\t" \
 "ds_read_b128 v[140:143], v88 offset:48\n\t" \
 "ds_read_b128 v[144:147], v88 offset:64\n\t" \
 "ds_read_b128 v[148:151], v88 offset:80\n\t" \
 "ds_read_b128 v[152:155], v88 offset:96\n\t" \
 "ds_read_b128 v[156:159], v88 offset:112\n\t" \
 "ds_read_b128 v[160:163], v88 offset:128\n\t" \
 "ds_read_b128 v[164:167], v88 offset:144\n\t" \
 "ds_read_b128 v[168:171], v88 offset:160\n\t" \
 "ds_read_b128 v[172:175], v88 offset:176\n\t" \
 "ds_read_b128 v[176:179], v88 offset:192\n\t" \
 "ds_read_b128 v[180:183], v88 offset:208\n\t" \
 "ds_read_b128 v[184:187], v88 offset:224\n\t" \
 "ds_read_b128 v[188:191], v88 offset:240\n\t"

// pk0: fresh-seeded by the x pair (v92:93, v93==0) as an explicit C operand.
#define PK_0_7 \
 "v_pk_fma_f32 v[76:77], v[128:129], v[12:13], v[92:93]\n\t" \
 PKM("78","79","130","131","14","15") \
 PKM("80","81","132","133","16","17") \
 PKM("82","83","134","135","18","19") \
 PKF("76","77","136","137","20","21") \
 PKF("78","79","138","139","22","23") \
 PKF("80","81","140","141","24","25") \
 PKF("82","83","142","143","26","27")
#define PK_8_15 \
 PKF("76","77","144","145","28","29") \
 PKF("78","79","146","147","30","31") \
 PKF("80","81","148","149","32","33") \
 PKF("82","83","150","151","34","35") \
 PKF("76","77","152","153","36","37") \
 PKF("78","79","154","155","38","39") \
 PKF("80","81","156","157","40","41") \
 PKF("82","83","158","159","42","43")
#define PK_16_23 \
 PKF("76","77","160","161","44","45") \
 PKF("78","79","162","163","46","47") \
 PKF("80","81","164","165","48","49") \
 PKF("82","83","166","167","50","51") \
 PKF("76","77","168","169","52","53") \
 PKF("78","79","170","171","54","55") \
 PKF("80","81","172","173","56","57") \
 PKF("82","83","174","175","58","59")
#define PK_24_31 \
 PKF("76","77","176","177","60","61") \
 PKF("78","79","178","179","62","63") \
 PKF("80","81","180","181","64","65") \
 PKF("82","83","182","183","66","67") \
 PKF("76","77","184","185","68","69") \
 PKF("78","79","186","187","70","71") \
 PKF("80","81","188","189","72","73") \
 PKF("82","83","190","191","74","75")

#define TAIL \
 "v_pk_add_f32 v[76:77], v[76:77], v[78:79]\n\t" \
 "v_pk_add_f32 v[80:81], v[80:81], v[82:83]\n\t" \
 "v_pk_add_f32 v[76:77], v[76:77], v[80:81]\n\t" \
 "v_add_f32 v84, v76, v77\n\t" \
 "v_max_f32 v84, 0, v84\n\t"

// Body at iteration t: v84 == h_{t-1}. Publish it, read it back broadcast,
// and during the DS latency window do all h-independent work (x seed for
// step t, prefetch of x two steps ahead). Then staged MACs. Wait math
// (17 DS ops this body: 1 write + 16 reads, in-order):
//   lgkmcnt(12): oldest 5 done = write + r0..r3  -> pk0..7  (v128-143)
//   lgkmcnt(8):  r4..r7  done -> pk8..15  (v144-159)
//   lgkmcnt(4):  r8..r11 done -> pk16..23 (v160-175)
//   lgkmcnt(0):  all     done -> pk24..31 (v176-191)
#define BODY(XL, XH, BUMP, LOADX) \
 "ds_write_b32 v86, v84\n\t" \
 RD16 \
 "s_waitcnt vmcnt(1)\n\t" \
 "v_mul_f32 v92, " XL ", v90\n\t" \
 "v_fmac_f32 v92, " XH ", v91\n\t" \
 BUMP \
 LOADX \
 "s_waitcnt lgkmcnt(12)\n\t" \
 PK_0_7 \
 "s_waitcnt lgkmcnt(8)\n\t" \
 PK_8_15 \
 "s_waitcnt lgkmcnt(4)\n\t" \
 PK_16_23 \
 "s_waitcnt lgkmcnt(0)\n\t" \
 PK_24_31 \
 TAIL

#define BUMP_EVEN \
 "v_add_u32 v100, 16, v100\n\t" \
 "v_min_u32 v100, 0x3ff0, v100\n\t"
#define LOAD_EVEN "global_load_dwordx2 v[96:97], v100, %[xb]\n\t"
#define LOAD_ODD  "global_load_dwordx2 v[98:99], v100, %[xb] offset:8\n\t"

__global__ __launch_bounds__(64, 1) void rnn_scan_kernel(
    const float* __restrict__ x,    // [B, T, 2]
    const float* __restrict__ Wh,   // [64, 64] row-major
    const float* __restrict__ Wx,   // [64, 2]
    float* __restrict__ out)        // [B]
{
    extern __shared__ float lds[];  // 64 floats (bytes 0..255)

    const int b = blockIdx.x;
    const int j = threadIdx.x;   // 0..63, lane == hidden/output index

    const float* xb = x + (size_t)b * TT * II;

    float h;
    asm volatile(
        // ---- prologue: W row j -> v12..v75 (pairs), wx -> v90:91 -----------
        "v_lshlrev_b32 v101, 8, %[lane]\n\t"       // j*256
        "global_load_dwordx4 v[12:15], v101, %[wh]\n\t"
        "global_load_dwordx4 v[16:19], v101, %[wh] offset:16\n\t"
        "global_load_dwordx4 v[20:23], v101, %[wh] offset:32\n\t"
        "global_load_dwordx4 v[24:27], v101, %[wh] offset:48\n\t"
        "global_load_dwordx4 v[28:31], v101, %[wh] offset:64\n\t"
        "global_load_dwordx4 v[32:35], v101, %[wh] offset:80\n\t"
        "global_load_dwordx4 v[36:39], v101, %[wh] offset:96\n\t"
        "global_load_dwordx4 v[40:43], v101, %[wh] offset:112\n\t"
        "global_load_dwordx4 v[44:47], v101, %[wh] offset:128\n\t"
        "global_load_dwordx4 v[48:51], v101, %[wh] offset:144\n\t"
        "global_load_dwordx4 v[52:55], v101, %[wh] offset:160\n\t"
        "global_load_dwordx4 v[56:59], v101, %[wh] offset:176\n\t"
        "global_load_dwordx4 v[60:63], v101, %[wh] offset:192\n\t"
        "global_load_dwordx4 v[64:67], v101, %[wh] offset:208\n\t"
        "global_load_dwordx4 v[68:71], v101, %[wh] offset:224\n\t"
        "global_load_dwordx4 v[72:75], v101, %[wh] offset:240\n\t"
        "v_lshlrev_b32 v102, 3, %[lane]\n\t"
        "global_load_dwordx2 v[90:91], v102, %[wx]\n\t"
        // x prefetch: even pair = x(t=0), odd pair = x(t=1)
        "v_mov_b32 v100, 0\n\t"
        "global_load_dwordx2 v[96:97], v100, %[xb]\n\t"
        "global_load_dwordx2 v[98:99], v100, %[xb] offset:8\n\t"
        // LDS addrs: write = lane*4, read = 0 (uniform broadcast)
        "v_lshlrev_b32 v86, 2, %[lane]\n\t"
        "v_mov_b32 v88, 0\n\t"
        // h_{-1} = 0; seed-C high half constant 0
        "v_mov_b32 v84, 0\n\t"
        "v_mov_b32 v93, 0\n\t"
        "s_movk_i32 s16, 0x400\n\t"
        "s_waitcnt vmcnt(2)\n\t"                    // W, wx done; 2 x in flight
        // ---- main loop: 1024 x (even body + odd body) = 2048 steps ---------
        "LTOP_%=:\n\t"
        BODY("v96", "v97", BUMP_EVEN, LOAD_EVEN)
        BODY("v98", "v99", , LOAD_ODD)
        "s_sub_u32 s16, s16, 1\n\t"
        "s_cmp_lg_u32 s16, 0\n\t"
        "s_cbranch_scc1 LTOP_%=\n\t"
        // ---- epilogue ------------------------------------------------------
        "s_waitcnt vmcnt(0) lgkmcnt(0)\n\t"
        "v_mov_b32 %[h], v84\n\t"
        : [h] "=&v"(h)
        : [lane] "v"(j), [wh] "s"(Wh), [xb] "s"(xb), [wx] "s"(Wx)
        : "memory", "scc",
          "v12","v13","v14","v15","v16","v17","v18","v19",
          "v20","v21","v22","v23","v24","v25","v26","v27",
          "v28","v29","v30","v31","v32","v33","v34","v35",
          "v36","v37","v38","v39","v40","v41","v42","v43",
          "v44","v45","v46","v47","v48","v49","v50","v51",
          "v52","v53","v54","v55","v56","v57","v58","v59",
          "v60","v61","v62","v63","v64","v65","v66","v67",
          "v68","v69","v70","v71","v72","v73","v74","v75",
          "v76","v77","v78","v79","v80","v81","v82","v83",
          "v84","v86","v88","v90","v91","v92","v93",
          "v96","v97","v98","v99","v100","v101","v102",
          "v128","v129","v130","v131","v132","v133","v134","v135",
          "v136","v137","v138","v139","v140","v141","v142","v143",
          "v144","v145","v146","v147","v148","v149","v150","v151",
          "v152","v153","v154","v155","v156","v157","v158","v159",
          "v160","v161","v162","v163","v164","v165","v166","v167",
          "v168","v169","v170","v171","v172","v173","v174","v175",
          "v176","v177","v178","v179","v180","v181","v182","v183",
          "v184","v185","v186","v187","v188","v189","v190","v191",
          "s16");

    // ||h_T||_2 across the wave (v84 = h[j] at lane j)
    float s = h * h;
#pragma unroll
    for (int off = 32; off > 0; off >>= 1)
        s += __shfl_xor(s, off, 64);
    if (j == 0)
        out[b] = sqrtf(s);
}

extern "C" void kernel_launch(void* const* d_in, const int* in_sizes, int n_in,
                              void* d_out, int out_size, void* d_ws, size_t ws_size,
                              hipStream_t stream) {
    const float* x  = (const float*)d_in[0];   // [B,T,2]
    const float* Wh = (const float*)d_in[1];   // [64,64]
    const float* Wx = (const float*)d_in[2];   // [64,2]
    float* out = (float*)d_out;                // [B]

    rnn_scan_kernel<<<dim3(BB), dim3(64), 256, stream>>>(x, Wh, Wx, out);
}